// Round 1
// baseline (258.649 us; speedup 1.0000x reference)
//
#include <hip/hip_runtime.h>
#include <hip/hip_bf16.h>

// Problem constants (fixed by setup_inputs)
#define N_NODES  50000
#define D_NODE   128
#define E_TOTAL  600000
#define IN_FEAT  256      // 2 * d_node
#define OUT_FEAT 128
#define BM       64       // edges per block (600000 / 64 = 9375 exact)
#define LDA      264      // padded LDS row for A (bf16 elems): stride 528B -> 2-way bank alias (free)
#define LDW      264      // padded LDS row for W
#define ALPHA_OFF (600000LL * 128LL)

typedef __bf16 bf16x8 __attribute__((ext_vector_type(8)));
typedef __bf16 bf16x4 __attribute__((ext_vector_type(4)));
typedef float  f32x4  __attribute__((ext_vector_type(4)));

// ---- prep: W_edge [128][256] f32 -> padded bf16 [128][264] in workspace ----
__global__ void convert_w(const float* __restrict__ W, __bf16* __restrict__ ws) {
    int idx = blockIdx.x * 256 + threadIdx.x;
    if (idx >= OUT_FEAT * LDW) return;
    int o = idx / LDW;
    int i = idx - o * LDW;
    float v = (i < IN_FEAT) ? W[o * IN_FEAT + i] : 0.0f;
    ws[idx] = (__bf16)v;
}

// ---- main: gathered GEMM + sigmoid, fused alpha=1 ----
// C[e][o] = sigmoid( sum_k feat[e][k] * W[o][k] ),  feat = [n_f[src] | n_f[dst]]
// MFMA 16x16x32 bf16: A[m][k] = feat, B[k][n] = W[n][k] (so B-frag reads are
// contiguous 16B from W's row-major layout).
__launch_bounds__(256)
__global__ void edge_kernel(const float* __restrict__ n_f,
                            const __bf16* __restrict__ wbf,
                            const int*   __restrict__ src_idx,
                            const int*   __restrict__ dst_idx,
                            float* __restrict__ out) {
    __shared__ __bf16 sW[OUT_FEAT * LDW];  // 67584 B
    __shared__ __bf16 sA[BM * LDA];        // 33792 B

    const int tid = threadIdx.x;
    const long long e0 = (long long)blockIdx.x * BM;

    // ---- stage W: flat 16B copies (4224 chunks) ----
    {
        const uint4* src = (const uint4*)wbf;
        uint4* dst = (uint4*)sW;
        #pragma unroll
        for (int i = 0; i < 17; ++i) {
            int idx = i * 256 + tid;
            if (idx < (OUT_FEAT * LDW * 2 / 16)) dst[idx] = src[idx];
        }
    }

    // ---- stage A: gather 64 edges, fp32 -> bf16 ----
    // thread t: row r = t>>2 (0..63), part p = t&3 ; p in {0,1} -> src half,
    // p in {2,3} -> dst half. Each part = 64 floats = 16x float4.
    {
        const int r = tid >> 2;
        const int p = tid & 3;
        const long long e = e0 + r;
        const int row = (p < 2) ? src_idx[e] : dst_idx[e];
        const float4* g = (const float4*)(n_f + (long long)row * D_NODE + (p & 1) * 64);
        bf16x4* dst = (bf16x4*)(sA + r * LDA + p * 64);
        #pragma unroll
        for (int j = 0; j < 16; ++j) {
            float4 v = g[j];
            bf16x4 h;
            h[0] = (__bf16)v.x; h[1] = (__bf16)v.y;
            h[2] = (__bf16)v.z; h[3] = (__bf16)v.w;
            dst[j] = h;
        }
    }

    // ---- alpha: softmax over size-1 axis == 1.0 exactly ----
    if (tid < BM) out[ALPHA_OFF + e0 + tid] = 1.0f;

    __syncthreads();

    // ---- compute: wave w owns rows [w*16, w*16+16) x all 128 cols ----
    const int w    = tid >> 6;
    const int lane = tid & 63;
    const int lr   = lane & 15;   // A-row / B-col within fragment
    const int lg   = lane >> 4;   // k-group (8 elems each)

    const __bf16* Ab = sA + (w * 16 + lr) * LDA + lg * 8;
    const __bf16* Wb = sW + lr * LDW + lg * 8;

    f32x4 acc[8];
    #pragma unroll
    for (int n = 0; n < 8; ++n) acc[n] = (f32x4){0.f, 0.f, 0.f, 0.f};

    #pragma unroll
    for (int kk = 0; kk < 8; ++kk) {               // K = 256 = 8 * 32
        bf16x8 a = *(const bf16x8*)(Ab + kk * 32);
        #pragma unroll
        for (int n = 0; n < 8; ++n) {              // N = 128 = 8 * 16
            bf16x8 b = *(const bf16x8*)(Wb + n * 16 * LDW + kk * 32);
            acc[n] = __builtin_amdgcn_mfma_f32_16x16x32_bf16(a, b, acc[n], 0, 0, 0);
        }
    }

    // ---- epilogue: sigmoid + store (C layout: col=lane&15, row=(lane>>4)*4+j) ----
    const long long ebase = e0 + w * 16 + lg * 4;
    #pragma unroll
    for (int n = 0; n < 8; ++n) {
        const int col = n * 16 + lr;
        #pragma unroll
        for (int j = 0; j < 4; ++j) {
            float x = acc[n][j];
            float s = 1.0f / (1.0f + __expf(-x));
            out[(ebase + j) * (long long)OUT_FEAT + col] = s;
        }
    }
}

extern "C" void kernel_launch(void* const* d_in, const int* in_sizes, int n_in,
                              void* d_out, int out_size, void* d_ws, size_t ws_size,
                              hipStream_t stream) {
    const float* n_f    = (const float*)d_in[0];
    const float* W_edge = (const float*)d_in[1];
    // d_in[2] = W_attn: mathematically dead (softmax over size-1 axis == 1)
    const int* src_idx  = (const int*)d_in[3];
    const int* dst_idx  = (const int*)d_in[4];
    float* out = (float*)d_out;
    __bf16* wbf = (__bf16*)d_ws;   // needs 67584 B

    convert_w<<<132, 256, 0, stream>>>(W_edge, wbf);
    edge_kernel<<<E_TOTAL / BM, 256, 0, stream>>>(n_f, wbf, src_idx, dst_idx, out);
}

// Round 2
// 182.329 us; speedup vs baseline: 1.4186x; 1.4186x over previous
//
#include <hip/hip_runtime.h>
#include <hip/hip_bf16.h>

// Problem constants (fixed by setup_inputs)
#define N_NODES  50000
#define D_NODE   128
#define E_TOTAL  600000
#define IN_FEAT  256      // 2 * d_node
#define OUT_FEAT 128
#define BM       64       // edges per block (600000 / 64 = 9375 exact)
#define ALPHA_OFF (600000LL * 128LL)

typedef __bf16 bf16x8 __attribute__((ext_vector_type(8)));
typedef float  f32x4  __attribute__((ext_vector_type(4)));

// ---- prep: W_edge [128][256] f32 -> per-fragment-swizzled bf16 layout ----
// wl[(((kk*8 + n)*64) + lane)*8 + j] = W[n*16 + (lane&15)][kk*32 + (lane>>4)*8 + j]
// so each wave's B-frag load for (kk,n) is one coalesced 1 KB global read.
__global__ void convert_w(const float* __restrict__ W, __bf16* __restrict__ wl) {
    int gid = blockIdx.x * 256 + threadIdx.x;   // 0..4095 (one bf16x8 each)
    int lane = gid & 63;
    int nk   = gid >> 6;        // 0..63
    int n    = nk & 7;
    int kk   = nk >> 3;
    int row  = n * 16 + (lane & 15);
    int col  = kk * 32 + (lane >> 4) * 8;
    const float* src = W + row * IN_FEAT + col;
    bf16x8 h;
    #pragma unroll
    for (int j = 0; j < 8; ++j) h[j] = (__bf16)src[j];
    *(bf16x8*)(wl + (long long)gid * 8) = h;
}

// ---- main: gathered GEMM + sigmoid, zero LDS, no barriers ----
// C[e][o] = sigmoid( sum_k feat[e][k] * W[o][k] ), feat = [n_f[src] | n_f[dst]]
// Wave w owns edges e0+w*16 .. +15 x all 128 cols. Each lane loads its MFMA
// A-fragment (A[lane&15][(lane>>4)*8+j], validated R1) straight from the
// gathered node row in global and converts f32->bf16 in-register.
__launch_bounds__(256)
__global__ void edge_kernel(const float* __restrict__ n_f,
                            const __bf16* __restrict__ wl,
                            const int*   __restrict__ src_idx,
                            const int*   __restrict__ dst_idx,
                            float* __restrict__ out) {
    const int tid  = threadIdx.x;
    const long long e0 = (long long)blockIdx.x * BM;
    const int w    = tid >> 6;
    const int lane = tid & 63;
    const int lr   = lane & 15;   // A-row / B-col within fragment
    const int lg   = lane >> 4;   // k-subgroup (8 elems each)

    // alpha: softmax over size-1 axis == 1.0 exactly
    if (tid < BM) out[ALPHA_OFF + e0 + tid] = 1.0f;

    const long long e = e0 + w * 16 + lr;
    const int sn = src_idx[e];
    const int dn = dst_idx[e];

    f32x4 acc[8];
    #pragma unroll
    for (int n = 0; n < 8; ++n) acc[n] = (f32x4){0.f, 0.f, 0.f, 0.f};

    #pragma unroll
    for (int kk = 0; kk < 8; ++kk) {               // K = 256 = 8 * 32
        const int node = (kk < 4) ? sn : dn;       // first half src, second dst
        const float* ap = n_f + (long long)node * D_NODE + (kk & 3) * 32 + lg * 8;
        float4 v0 = *(const float4*)ap;
        float4 v1 = *(const float4*)(ap + 4);
        bf16x8 a;
        a[0] = (__bf16)v0.x; a[1] = (__bf16)v0.y;
        a[2] = (__bf16)v0.z; a[3] = (__bf16)v0.w;
        a[4] = (__bf16)v1.x; a[5] = (__bf16)v1.y;
        a[6] = (__bf16)v1.z; a[7] = (__bf16)v1.w;

        const bf16x8* bp = (const bf16x8*)(wl) + (long long)(kk * 8) * 64 + lane;
        #pragma unroll
        for (int n = 0; n < 8; ++n) {              // N = 128 = 8 * 16
            bf16x8 b = bp[n * 64];                 // coalesced 1 KB wave load
            acc[n] = __builtin_amdgcn_mfma_f32_16x16x32_bf16(a, b, acc[n], 0, 0, 0);
        }
    }

    // ---- epilogue: sigmoid + store (C layout: col=lane&15, row=(lane>>4)*4+j) ----
    const long long ebase = e0 + w * 16 + lg * 4;
    #pragma unroll
    for (int n = 0; n < 8; ++n) {
        const int col = n * 16 + lr;
        #pragma unroll
        for (int j = 0; j < 4; ++j) {
            float x = acc[n][j];
            float s = 1.0f / (1.0f + __expf(-x));
            out[(ebase + j) * (long long)OUT_FEAT + col] = s;
        }
    }
}

extern "C" void kernel_launch(void* const* d_in, const int* in_sizes, int n_in,
                              void* d_out, int out_size, void* d_ws, size_t ws_size,
                              hipStream_t stream) {
    const float* n_f    = (const float*)d_in[0];
    const float* W_edge = (const float*)d_in[1];
    // d_in[2] = W_attn: mathematically dead (softmax over size-1 axis == 1)
    const int* src_idx  = (const int*)d_in[3];
    const int* dst_idx  = (const int*)d_in[4];
    float* out = (float*)d_out;
    __bf16* wl = (__bf16*)d_ws;   // needs 65536 B

    convert_w<<<16, 256, 0, stream>>>(W_edge, wl);
    edge_kernel<<<E_TOTAL / BM, 256, 0, stream>>>(n_f, wl, src_idx, dst_idx, out);
}

// Round 3
// 160.507 us; speedup vs baseline: 1.6115x; 1.1360x over previous
//
#include <hip/hip_runtime.h>
#include <hip/hip_bf16.h>

// Problem constants (fixed by setup_inputs)
#define N_NODES  50000
#define D_NODE   128
#define E_TOTAL  600000
#define IN_FEAT  256      // 2 * d_node
#define OUT_FEAT 128
#define BM       64       // edges per block (1 wave); 600000/64 = 9375 exact
#define ALPHA_OFF (600000 * 128)   // fits in int32 (77.4M)

typedef __bf16 bf16x8 __attribute__((ext_vector_type(8)));
typedef float  f32x4  __attribute__((ext_vector_type(4)));

// ---- prep: W_edge [128][256] f32 -> per-fragment-swizzled bf16 layout ----
// wl[(((kk*8 + n)*64) + lane)*8 + j] = W[n*16 + (lane&15)][kk*32 + (lane>>4)*8 + j]
// so each wave's B-frag load for (kk,n) is one coalesced 1 KB global read.
__global__ void convert_w(const float* __restrict__ W, __bf16* __restrict__ wl) {
    int gid = blockIdx.x * 256 + threadIdx.x;   // 0..4095 (one bf16x8 each)
    int lane = gid & 63;
    int nk   = gid >> 6;        // 0..63
    int n    = nk & 7;
    int kk   = nk >> 3;
    int row  = n * 16 + (lane & 15);
    int col  = kk * 32 + (lane >> 4) * 8;
    const float* src = W + row * IN_FEAT + col;
    bf16x8 h;
    #pragma unroll
    for (int j = 0; j < 8; ++j) h[j] = (__bf16)src[j];
    *(bf16x8*)(wl + gid * 8) = h;
}

// ---- main: gathered GEMM + sigmoid, zero LDS, one wave = 64 edges ----
// C[e][o] = sigmoid( sum_k feat[e][k] * W[o][k] ), feat = [n_f[src] | n_f[dst]]
// M-blocking: 4 row-groups of 16 edges share every B-frag load, so W (64KB)
// is read once per 64 edges (was once per 16) -> B L1/L2 traffic / 4.
__launch_bounds__(64, 2)
__global__ void edge_kernel(const float* __restrict__ n_f,
                            const __bf16* __restrict__ wl,
                            const int*   __restrict__ src_idx,
                            const int*   __restrict__ dst_idx,
                            float* __restrict__ out) {
    const int lane = threadIdx.x;      // one wave per block
    const int e0   = blockIdx.x * BM;
    const int lr   = lane & 15;        // A-row / B-col within fragment
    const int lg   = lane >> 4;        // k-subgroup (8 elems each)

    // alpha: softmax over size-1 axis == 1.0 exactly
    out[ALPHA_OFF + e0 + lane] = 1.0f;

    // Per-lane gather rows for the 4 row-groups (8 independent streams)
    int sn[4], dn[4];
    #pragma unroll
    for (int r = 0; r < 4; ++r) {
        const int e = e0 + r * 16 + lr;
        sn[r] = src_idx[e];
        dn[r] = dst_idx[e];
    }

    f32x4 acc[4][8];
    #pragma unroll
    for (int r = 0; r < 4; ++r)
        #pragma unroll
        for (int n = 0; n < 8; ++n) acc[r][n] = (f32x4){0.f, 0.f, 0.f, 0.f};

    #pragma unroll
    for (int kk = 0; kk < 8; ++kk) {               // K = 256 = 8 * 32
        bf16x8 a[4];
        #pragma unroll
        for (int r = 0; r < 4; ++r) {
            const int node = (kk < 4) ? sn[r] : dn[r];
            const float* ap = n_f + node * D_NODE + (kk & 3) * 32 + lg * 8;
            float4 v0 = *(const float4*)ap;
            float4 v1 = *(const float4*)(ap + 4);
            a[r][0] = (__bf16)v0.x; a[r][1] = (__bf16)v0.y;
            a[r][2] = (__bf16)v0.z; a[r][3] = (__bf16)v0.w;
            a[r][4] = (__bf16)v1.x; a[r][5] = (__bf16)v1.y;
            a[r][6] = (__bf16)v1.z; a[r][7] = (__bf16)v1.w;
        }
        const bf16x8* bp = (const bf16x8*)(wl) + kk * 8 * 64 + lane;
        #pragma unroll
        for (int n = 0; n < 8; ++n) {              // N = 128 = 8 * 16
            bf16x8 b = bp[n * 64];                 // coalesced 1 KB wave load
            #pragma unroll
            for (int r = 0; r < 4; ++r)
                acc[r][n] = __builtin_amdgcn_mfma_f32_16x16x32_bf16(a[r], b, acc[r][n], 0, 0, 0);
        }
    }

    // ---- epilogue: sigmoid + store (C layout: col=lane&15, row=(lane>>4)*4+j) ----
    #pragma unroll
    for (int r = 0; r < 4; ++r) {
        const int ebase = e0 + r * 16 + lg * 4;
        #pragma unroll
        for (int n = 0; n < 8; ++n) {
            const int col = n * 16 + lr;
            #pragma unroll
            for (int j = 0; j < 4; ++j) {
                float x = acc[r][n][j];
                float s = __builtin_amdgcn_rcpf(1.0f + __expf(-x));
                out[(ebase + j) * OUT_FEAT + col] = s;
            }
        }
    }
}

extern "C" void kernel_launch(void* const* d_in, const int* in_sizes, int n_in,
                              void* d_out, int out_size, void* d_ws, size_t ws_size,
                              hipStream_t stream) {
    const float* n_f    = (const float*)d_in[0];
    const float* W_edge = (const float*)d_in[1];
    // d_in[2] = W_attn: mathematically dead (softmax over size-1 axis == 1)
    const int* src_idx  = (const int*)d_in[3];
    const int* dst_idx  = (const int*)d_in[4];
    float* out = (float*)d_out;
    __bf16* wl = (__bf16*)d_ws;   // needs 65536 B

    convert_w<<<16, 256, 0, stream>>>(W_edge, wl);
    edge_kernel<<<E_TOTAL / BM, 64, 0, stream>>>(n_f, wl, src_idx, dst_idx, out);
}

// Round 4
// 139.504 us; speedup vs baseline: 1.8541x; 1.1506x over previous
//
#include <hip/hip_runtime.h>
#include <hip/hip_bf16.h>

// Problem constants (fixed by setup_inputs)
#define N_NODES  50000
#define D_NODE   128
#define E_TOTAL  600000
#define IN_FEAT  256      // 2 * d_node
#define OUT_FEAT 128
#define ALPHA_OFF (600000 * 128)   // fits in int32 (77.4M)

typedef __bf16 bf16x8 __attribute__((ext_vector_type(8)));
typedef float  f32x4  __attribute__((ext_vector_type(4)));

// ================= FAST PATH =================
// sigmoid(W.[nf_src|nf_dst]) = sigmoid(zs[src] + zd[dst]),
//   zs = n_f @ W[:, :128]^T,  zd = n_f @ W[:, 128:]^T  (per-node, reused ~12x/node)
// Z stored bf16 [N_NODES][256] (zs cols 0..127, zd cols 128..255) = 25.6 MB.

// ---- prep: Wcat -> per-fragment-swizzled bf16 (for the node-projection GEMM) ----
// Wcat[o2][k2] = o2<128 ? W[o2][k2] : W[o2-128][128+k2]   (o2<256, k2<128)
// wl[(((kk*16 + n)*64) + lane)*8 + j] = Wcat[n*16 + (lane&15)][kk*32 + (lane>>4)*8 + j]
__global__ void convert_wcat(const float* __restrict__ W, __bf16* __restrict__ wl) {
    int gid  = blockIdx.x * 256 + threadIdx.x;   // 0..4095, one bf16x8 each
    int lane = gid & 63;
    int nk   = gid >> 6;        // 0..63
    int n    = nk & 15;         // 16 col-groups (N=256)
    int kk   = nk >> 4;         // 0..3       (K=128)
    int o2   = n * 16 + (lane & 15);
    int k2   = kk * 32 + (lane >> 4) * 8;
    const float* src = (o2 < 128) ? (W + o2 * IN_FEAT + k2)
                                  : (W + (o2 - 128) * IN_FEAT + 128 + k2);
    bf16x8 h;
    #pragma unroll
    for (int j = 0; j < 8; ++j) h[j] = (__bf16)src[j];
    *(bf16x8*)(wl + gid * 8) = h;
}

// ---- node projection: Z[v][o2] = sum_k n_f[v][k] * Wcat[o2][k] ----
// one wave = 16 nodes x 256 cols, K=128. 50000 = 3125 * 16 exact.
__launch_bounds__(64)
__global__ void zgemm(const float* __restrict__ n_f,
                      const __bf16* __restrict__ wl,
                      __bf16* __restrict__ Z) {
    const int lane = threadIdx.x;
    const int v0   = blockIdx.x * 16;
    const int lr   = lane & 15;
    const int lg   = lane >> 4;

    f32x4 acc[16];
    #pragma unroll
    for (int n = 0; n < 16; ++n) acc[n] = (f32x4){0.f, 0.f, 0.f, 0.f};

    #pragma unroll
    for (int kk = 0; kk < 4; ++kk) {               // K = 128 = 4 * 32
        const float* ap = n_f + (v0 + lr) * D_NODE + kk * 32 + lg * 8;
        float4 v0f = *(const float4*)ap;
        float4 v1f = *(const float4*)(ap + 4);
        bf16x8 a;
        a[0] = (__bf16)v0f.x; a[1] = (__bf16)v0f.y;
        a[2] = (__bf16)v0f.z; a[3] = (__bf16)v0f.w;
        a[4] = (__bf16)v1f.x; a[5] = (__bf16)v1f.y;
        a[6] = (__bf16)v1f.z; a[7] = (__bf16)v1f.w;
        const bf16x8* bp = (const bf16x8*)(wl) + kk * 16 * 64 + lane;
        #pragma unroll
        for (int n = 0; n < 16; ++n) {             // N = 256 = 16 * 16
            bf16x8 b = bp[n * 64];
            acc[n] = __builtin_amdgcn_mfma_f32_16x16x32_bf16(a, b, acc[n], 0, 0, 0);
        }
    }

    // C layout: col = n*16 + (lane&15), row = (lane>>4)*4 + j
    #pragma unroll
    for (int n = 0; n < 16; ++n) {
        const int col = n * 16 + lr;
        #pragma unroll
        for (int j = 0; j < 4; ++j)
            Z[(v0 + lg * 4 + j) * 256 + col] = (__bf16)acc[n][j];
    }
}

// ---- edge apply: out[e][o] = sigmoid( Z[src][o] + Z[dst][128+o] ) ----
// 8 lanes per edge, 16 cols each. 600000 / 32 edges-per-block = 18750 exact.
__launch_bounds__(256)
__global__ void edge_apply(const __bf16* __restrict__ Z,
                           const int* __restrict__ src_idx,
                           const int* __restrict__ dst_idx,
                           float* __restrict__ out) {
    const int e   = blockIdx.x * 32 + (threadIdx.x >> 3);
    const int sub = threadIdx.x & 7;
    const int sv  = src_idx[e];
    const int dv  = dst_idx[e];

    if (sub == 0) out[ALPHA_OFF + e] = 1.0f;   // softmax over size-1 axis == 1

    const __bf16* zs = Z + sv * 256 + sub * 16;
    const __bf16* zd = Z + dv * 256 + 128 + sub * 16;
    bf16x8 s0 = *(const bf16x8*)(zs);
    bf16x8 s1 = *(const bf16x8*)(zs + 8);
    bf16x8 d0 = *(const bf16x8*)(zd);
    bf16x8 d1 = *(const bf16x8*)(zd + 8);

    float r[16];
    #pragma unroll
    for (int j = 0; j < 8; ++j) {
        float x0 = (float)s0[j] + (float)d0[j];
        float x1 = (float)s1[j] + (float)d1[j];
        r[j]     = __builtin_amdgcn_rcpf(1.0f + __expf(-x0));
        r[8 + j] = __builtin_amdgcn_rcpf(1.0f + __expf(-x1));
    }
    float4* o = (float4*)(out + e * OUT_FEAT + sub * 16);
    #pragma unroll
    for (int q = 0; q < 4; ++q)
        o[q] = (float4){r[q * 4], r[q * 4 + 1], r[q * 4 + 2], r[q * 4 + 3]};
}

// ================= FALLBACK PATH (R3, needs only 64 KB ws) =================
__global__ void convert_w_fb(const float* __restrict__ W, __bf16* __restrict__ wl) {
    int gid = blockIdx.x * 256 + threadIdx.x;
    int lane = gid & 63;
    int nk   = gid >> 6;
    int n    = nk & 7;
    int kk   = nk >> 3;
    int row  = n * 16 + (lane & 15);
    int col  = kk * 32 + (lane >> 4) * 8;
    const float* src = W + row * IN_FEAT + col;
    bf16x8 h;
    #pragma unroll
    for (int j = 0; j < 8; ++j) h[j] = (__bf16)src[j];
    *(bf16x8*)(wl + gid * 8) = h;
}

__launch_bounds__(64, 2)
__global__ void edge_kernel_fb(const float* __restrict__ n_f,
                               const __bf16* __restrict__ wl,
                               const int*   __restrict__ src_idx,
                               const int*   __restrict__ dst_idx,
                               float* __restrict__ out) {
    const int lane = threadIdx.x;
    const int e0   = blockIdx.x * 64;
    const int lr   = lane & 15;
    const int lg   = lane >> 4;

    out[ALPHA_OFF + e0 + lane] = 1.0f;

    int sn[4], dn[4];
    #pragma unroll
    for (int r = 0; r < 4; ++r) {
        const int e = e0 + r * 16 + lr;
        sn[r] = src_idx[e];
        dn[r] = dst_idx[e];
    }
    f32x4 acc[4][8];
    #pragma unroll
    for (int r = 0; r < 4; ++r)
        #pragma unroll
        for (int n = 0; n < 8; ++n) acc[r][n] = (f32x4){0.f, 0.f, 0.f, 0.f};

    #pragma unroll
    for (int kk = 0; kk < 8; ++kk) {
        bf16x8 a[4];
        #pragma unroll
        for (int r = 0; r < 4; ++r) {
            const int node = (kk < 4) ? sn[r] : dn[r];
            const float* ap = n_f + node * D_NODE + (kk & 3) * 32 + lg * 8;
            float4 u0 = *(const float4*)ap;
            float4 u1 = *(const float4*)(ap + 4);
            a[r][0] = (__bf16)u0.x; a[r][1] = (__bf16)u0.y;
            a[r][2] = (__bf16)u0.z; a[r][3] = (__bf16)u0.w;
            a[r][4] = (__bf16)u1.x; a[r][5] = (__bf16)u1.y;
            a[r][6] = (__bf16)u1.z; a[r][7] = (__bf16)u1.w;
        }
        const bf16x8* bp = (const bf16x8*)(wl) + kk * 8 * 64 + lane;
        #pragma unroll
        for (int n = 0; n < 8; ++n) {
            bf16x8 b = bp[n * 64];
            #pragma unroll
            for (int r = 0; r < 4; ++r)
                acc[r][n] = __builtin_amdgcn_mfma_f32_16x16x32_bf16(a[r], b, acc[r][n], 0, 0, 0);
        }
    }
    #pragma unroll
    for (int r = 0; r < 4; ++r) {
        const int ebase = e0 + r * 16 + lg * 4;
        #pragma unroll
        for (int n = 0; n < 8; ++n) {
            const int col = n * 16 + lr;
            #pragma unroll
            for (int j = 0; j < 4; ++j) {
                float x = acc[r][n][j];
                out[(ebase + j) * OUT_FEAT + col] = __builtin_amdgcn_rcpf(1.0f + __expf(-x));
            }
        }
    }
}

extern "C" void kernel_launch(void* const* d_in, const int* in_sizes, int n_in,
                              void* d_out, int out_size, void* d_ws, size_t ws_size,
                              hipStream_t stream) {
    const float* n_f    = (const float*)d_in[0];
    const float* W_edge = (const float*)d_in[1];
    // d_in[2] = W_attn: mathematically dead (softmax over size-1 axis == 1)
    const int* src_idx  = (const int*)d_in[3];
    const int* dst_idx  = (const int*)d_in[4];
    float* out = (float*)d_out;

    const size_t need = 65536 + (size_t)N_NODES * 256 * sizeof(__bf16);  // wl + Z
    if (ws_size >= need) {
        __bf16* wl = (__bf16*)d_ws;                       // 64 KB
        __bf16* Z  = (__bf16*)((char*)d_ws + 65536);      // 25.6 MB
        convert_wcat<<<16, 256, 0, stream>>>(W_edge, wl);
        zgemm<<<N_NODES / 16, 64, 0, stream>>>(n_f, wl, Z);
        edge_apply<<<E_TOTAL / 32, 256, 0, stream>>>(Z, src_idx, dst_idx, out);
    } else {
        __bf16* wl = (__bf16*)d_ws;                       // 64 KB
        convert_w_fb<<<16, 256, 0, stream>>>(W_edge, wl);
        edge_kernel_fb<<<E_TOTAL / 64, 64, 0, stream>>>(n_f, wl, src_idx, dst_idx, out);
    }
}